// Round 5
// baseline (377.552 us; speedup 1.0000x reference)
//
#include <hip/hip_runtime.h>

#define HW_ 65536
#define W_ 1024
#define H_ 64
#define B_ 2
#define C_ 68
#define NPIX 131072
#define NBLK_F 512
#define EPS 1e-5f

typedef __attribute__((ext_vector_type(8))) short short8;
typedef __attribute__((ext_vector_type(4))) float floatx4;

__device__ __forceinline__ unsigned short f2bf(float f) {
  unsigned u = __float_as_uint(f);
  u += 0x7fffu + ((u >> 16) & 1u);
  return (unsigned short)(u >> 16);
}
__device__ __forceinline__ unsigned pack2(float a, float b) {
  return (unsigned)f2bf(a) | ((unsigned)f2bf(b) << 16);
}
__device__ __forceinline__ float wred(float v) {
  v += __shfl_xor(v, 1);  v += __shfl_xor(v, 2);  v += __shfl_xor(v, 4);
  v += __shfl_xor(v, 8);  v += __shfl_xor(v, 16); v += __shfl_xor(v, 32);
  return v;
}
__device__ __forceinline__ int swz_tile(int bid) {
  // XCD-contiguous: XCD j (= bid%8) owns tiles [j*64, j*64+64)
  return (bid & 7) * 64 + (bid >> 3);
}
__device__ __forceinline__ float wsld(const float* p) {
  return __hip_atomic_load(p, __ATOMIC_RELAXED, __HIP_MEMORY_SCOPE_AGENT);
}

// Sense-reversing grid barrier (proven R2). bar[0]=count, bar[1]=generation.
__device__ __forceinline__ void gridbar(unsigned* bar, unsigned nblk) {
  __syncthreads();
  if (threadIdx.x == 0) {
    __threadfence();
    unsigned gen = __hip_atomic_load(&bar[1], __ATOMIC_RELAXED, __HIP_MEMORY_SCOPE_AGENT);
    unsigned arrived =
        __hip_atomic_fetch_add(&bar[0], 1u, __ATOMIC_ACQ_REL, __HIP_MEMORY_SCOPE_AGENT);
    if (arrived == nblk - 1) {
      __hip_atomic_store(&bar[0], 0u, __ATOMIC_RELAXED, __HIP_MEMORY_SCOPE_AGENT);
      __hip_atomic_store(&bar[1], gen + 1u, __ATOMIC_RELEASE, __HIP_MEMORY_SCOPE_AGENT);
    } else {
      long long spins = 0;
      while (__hip_atomic_load(&bar[1], __ATOMIC_ACQUIRE, __HIP_MEMORY_SCOPE_AGENT) == gen) {
        if (++spins > (1LL << 22)) break;  // safety valve
        __builtin_amdgcn_s_sleep(8);
      }
    }
    __threadfence();
  }
  __syncthreads();
}

// neighbor ownership for 4-way split: q0:{0,1,2} q1:{3,4} q2:{5,6} q3:{7,8}
__device__ __forceinline__ bool owns_k(int quarter, int k) {
  return (quarter == 0) ? (k < 3)
       : (quarter == 1) ? (k >= 3 && k < 5)
       : (quarter == 2) ? (k >= 5 && k < 7)
       :                  (k >= 7);
}

// ---- K1: stats1, 4 threads/pixel (grid 2048): 32 waves/CU ----
__global__ __launch_bounds__(256) void k_stats1(
    const float* __restrict__ x, const float* __restrict__ mask,
    const float* __restrict__ w1, const float* __restrict__ g1,
    float* __restrict__ ws) {
  int quarter = blockIdx.x >> 9;
  int p = swz_tile(blockIdx.x & 511) * 256 + threadIdx.x;
  int b = p >> 16, s = p & (HW_ - 1);
  int h = s >> 10, w = s & (W_ - 1);
  const float* xb = x + (size_t)b * C_ * HW_;
  const float* mb = mask + (size_t)b * HW_;
  float xc0 = xb[s], xc1 = xb[HW_ + s], xc2 = xb[2 * HW_ + s], xc3 = xb[3 * HW_ + s];

  float acc[34];
#pragma unroll
  for (int i = 0; i < 34; i++) acc[i] = 0.f;
  if (quarter == 1) acc[33] = (mb[s] > 0.f) ? 1.f : 0.f;  // center mask (once)

#pragma unroll
  for (int k = 0; k < 9; k++) {
    if (!owns_k(quarter, k)) continue;
    int di = k / 3 - 1, dj = k % 3 - 1;
    int hh = h + di, ww = w + dj;
    bool inb = ((unsigned)hh < (unsigned)H_) && ((unsigned)ww < (unsigned)W_);
    int ns = hh * W_ + ww;
    float mval = inb ? mb[ns] : 0.f;
    if (mval > 0.f) {
      float pn0 = xb[ns] - xc0;
      float pn1 = xb[HW_ + ns] - xc1;
      float pn2 = xb[2 * HW_ + ns] - xc2;
      float pn3 = xb[3 * HW_ + ns] - xc3;
      acc[32] += 1.f;
#pragma unroll
      for (int o = 0; o < 8; o++) {
        float ta = pn0 * w1[o * 4] + pn1 * w1[o * 4 + 1] + pn2 * w1[o * 4 + 2] + pn3 * w1[o * 4 + 3];
        acc[o] += ta; acc[8 + o] += ta * ta;
        float tg = pn0 * g1[o * 4] + pn1 * g1[o * 4 + 1] + pn2 * g1[o * 4 + 2] + pn3 * g1[o * 4 + 3];
        acc[16 + o] += tg; acc[24 + o] += tg * tg;
      }
    }
  }
  __shared__ float red[4][34];
  int lane = threadIdx.x & 63, wave = threadIdx.x >> 6;
#pragma unroll
  for (int i = 0; i < 34; i++) {
    float rv = wred(acc[i]);
    if (lane == 0) red[wave][i] = rv;
  }
  __syncthreads();
  if (threadIdx.x < 34)
    atomicAdd(&ws[threadIdx.x],
              red[0][threadIdx.x] + red[1][threadIdx.x] + red[2][threadIdx.x] + red[3][threadIdx.x]);
}

// ---- K2: stats2, same 4-way split (grid 2048) ----
__global__ __launch_bounds__(256) void k_stats2(
    const float* __restrict__ x, const float* __restrict__ mask,
    const float* __restrict__ g1, const float* __restrict__ gbn1_g,
    const float* __restrict__ gbn1_b, const float* __restrict__ g2,
    float* __restrict__ ws) {
  __shared__ float sc[8], sh[8];
  if (threadIdx.x < 8) {
    int o = threadIdx.x;
    float n = fmaxf(ws[32], 1.f);
    float mean = ws[16 + o] / n;
    float var = ws[24 + o] / n - mean * mean;
    float s_ = gbn1_g[o] * rsqrtf(var + EPS);
    sc[o] = s_; sh[o] = gbn1_b[o] - mean * s_;
  }
  __syncthreads();

  int quarter = blockIdx.x >> 9;
  int p = swz_tile(blockIdx.x & 511) * 256 + threadIdx.x;
  int b = p >> 16, s = p & (HW_ - 1);
  int h = s >> 10, w = s & (W_ - 1);
  const float* xb = x + (size_t)b * C_ * HW_;
  const float* mb = mask + (size_t)b * HW_;
  float xc0 = xb[s], xc1 = xb[HW_ + s], xc2 = xb[2 * HW_ + s], xc3 = xb[3 * HW_ + s];

  float acc2[16];
#pragma unroll
  for (int i = 0; i < 16; i++) acc2[i] = 0.f;

#pragma unroll
  for (int k = 0; k < 9; k++) {
    if (!owns_k(quarter, k)) continue;
    int di = k / 3 - 1, dj = k % 3 - 1;
    int hh = h + di, ww = w + dj;
    bool inb = ((unsigned)hh < (unsigned)H_) && ((unsigned)ww < (unsigned)W_);
    int ns = hh * W_ + ww;
    float mval = inb ? mb[ns] : 0.f;
    if (mval > 0.f) {
      float pn0 = xb[ns] - xc0;
      float pn1 = xb[HW_ + ns] - xc1;
      float pn2 = xb[2 * HW_ + ns] - xc2;
      float pn3 = xb[3 * HW_ + ns] - xc3;
      float gb[8];
#pragma unroll
      for (int o = 0; o < 8; o++) {
        float tg = pn0 * g1[o * 4] + pn1 * g1[o * 4 + 1] + pn2 * g1[o * 4 + 2] + pn3 * g1[o * 4 + 3];
        gb[o] = fmaxf(sc[o] * tg + sh[o], 0.f);
      }
#pragma unroll
      for (int j = 0; j < 8; j++) {
        float t2 = 0.f;
#pragma unroll
        for (int o = 0; o < 8; o++) t2 += gb[o] * g2[j * 8 + o];
        acc2[j] += t2; acc2[8 + j] += t2 * t2;
      }
    }
  }
  __shared__ float red[4][16];
  int lane = threadIdx.x & 63, wave = threadIdx.x >> 6;
#pragma unroll
  for (int i = 0; i < 16; i++) {
    float rv = wred(acc2[i]);
    if (lane == 0) red[wave][i] = rv;
  }
  __syncthreads();
  if (threadIdx.x < 16)
    atomicAdd(&ws[40 + threadIdx.x],
              red[0][threadIdx.x] + red[1][threadIdx.x] + red[2][threadIdx.x] + red[3][threadIdx.x]);
}

// --------- K3: fused kernel, 512 thr / 256 pixels, + gridbar + abn apply ----
// half 0: neighbors k=0..4; half 1: k=5..8. fagg split by channel (32 each).
// GEMM: 8 waves = 4 m-groups x 2 n-groups. After abn sums: gridbar, then
// apply abn + relu + center-mask zero from registers, store directly to out.
__global__ __launch_bounds__(512, 4) void k_fused(
    const float* __restrict__ x, const float* __restrict__ mask,
    const float* __restrict__ w1, const float* __restrict__ bn1_g,
    const float* __restrict__ bn1_b, const float* __restrict__ w2,
    const float* __restrict__ b2, const float* __restrict__ g1,
    const float* __restrict__ gbn1_g, const float* __restrict__ gbn1_b,
    const float* __restrict__ g2, const float* __restrict__ gbn2_g,
    const float* __restrict__ gbn2_b, const float* __restrict__ w_agg,
    const float* __restrict__ abn_g, const float* __restrict__ abn_b,
    float* __restrict__ ws, float* __restrict__ out) {
  unsigned* bar = (unsigned*)(ws + 248);
  __shared__ uint4 vecA[17][256];   // 69.6 KB : K-major bf16 chunks
  __shared__ float evb[9][256];     // 9 KB   : softmax logit exchange
  __shared__ float sA[8], hA[8], sG1[8], hG1[8], sG2[8], hG2[8];
  __shared__ float scD[64], shD[64];

  if (threadIdx.x < 24) {
    int o = threadIdx.x & 7;
    float n = fmaxf(ws[32], 1.f);
    float sum, sum2, gma, bta;
    if (threadIdx.x < 8)       { sum = ws[o];      sum2 = ws[8 + o];  gma = bn1_g[o];  bta = bn1_b[o]; }
    else if (threadIdx.x < 16) { sum = ws[16 + o]; sum2 = ws[24 + o]; gma = gbn1_g[o]; bta = gbn1_b[o]; }
    else                       { sum = ws[40 + o]; sum2 = ws[48 + o]; gma = gbn2_g[o]; bta = gbn2_b[o]; }
    float mean = sum / n, var = sum2 / n - mean * mean;
    float s_ = gma * rsqrtf(var + EPS);
    float sft = bta - mean * s_;
    if (threadIdx.x < 8)       { sA[o] = s_;  hA[o] = sft; }
    else if (threadIdx.x < 16) { sG1[o] = s_; hG1[o] = sft; }
    else                       { sG2[o] = s_; hG2[o] = sft; }
  }
  __syncthreads();

  int tid = threadIdx.x;
  int half = tid >> 8;      // 0: k 0..4, 1: k 5..8  (wave-uniform)
  int pix = tid & 255;
  int tile = swz_tile(blockIdx.x);
  int p0 = tile * 256;
  int p = p0 + pix;
  int b = p >> 16, s = p & (HW_ - 1);
  int h = s >> 10, w = s & (W_ - 1);
  const float* xb = x + (size_t)b * C_ * HW_;
  const float* mb = mask + (size_t)b * HW_;
  float xc0 = xb[s], xc1 = xb[HW_ + s], xc2 = xb[2 * HW_ + s], xc3 = xb[3 * HW_ + s];
  float b2v = b2[0];

  // ---- phase 1: softmax logits for my neighbors ----
  unsigned mbits = 0u;
#pragma unroll
  for (int k = 0; k < 9; k++) {
    bool mine = (k < 5) ? (half == 0) : (half == 1);
    if (!mine) continue;
    int di = k / 3 - 1, dj = k % 3 - 1;
    int hh = h + di, ww = w + dj;
    bool inb = ((unsigned)hh < (unsigned)H_) && ((unsigned)ww < (unsigned)W_);
    int ns = hh * W_ + ww;
    float mval = inb ? mb[ns] : 0.f;
    float wp = 0.f;
    if (mval > 0.f) {
      mbits |= (1u << k);
      float pn0 = xb[ns] - xc0;
      float pn1 = xb[HW_ + ns] - xc1;
      float pn2 = xb[2 * HW_ + ns] - xc2;
      float pn3 = xb[3 * HW_ + ns] - xc3;
      float accw = 0.f;
#pragma unroll
      for (int o = 0; o < 8; o++) {
        float ta = pn0 * w1[o * 4] + pn1 * w1[o * 4 + 1] + pn2 * w1[o * 4 + 2] + pn3 * w1[o * 4 + 3];
        accw += fmaxf(sA[o] * ta + hA[o], 0.f) * w2[o];
      }
      wp = accw + b2v;
    }
    evb[k][pix] = wp;
  }
  __syncthreads();

  // ---- phase 2: both halves compute identical softmax weights ----
  float ev[9];
  float mx = -1e30f;
#pragma unroll
  for (int k = 0; k < 9; k++) { ev[k] = evb[k][pix]; mx = fmaxf(mx, ev[k]); }
  float den = 0.f;
#pragma unroll
  for (int k = 0; k < 9; k++) { ev[k] = __expf(ev[k] - mx); den += ev[k]; }
  float inv = 1.f / den;

  // ---- phase 3: g-vec for my neighbors ----
#pragma unroll
  for (int k = 0; k < 9; k++) {
    bool mine = (k < 5) ? (half == 0) : (half == 1);
    if (!mine) continue;
    uint4 pk; pk.x = pk.y = pk.z = pk.w = 0u;
    if ((mbits >> k) & 1u) {
      int di = k / 3 - 1, dj = k % 3 - 1;
      int ns = (h + di) * W_ + (w + dj);
      float wt = ev[k] * inv;
      float pn0 = xb[ns] - xc0;
      float pn1 = xb[HW_ + ns] - xc1;
      float pn2 = xb[2 * HW_ + ns] - xc2;
      float pn3 = xb[3 * HW_ + ns] - xc3;
      float gb[8];
#pragma unroll
      for (int o = 0; o < 8; o++) {
        float tg = pn0 * g1[o * 4] + pn1 * g1[o * 4 + 1] + pn2 * g1[o * 4 + 2] + pn3 * g1[o * 4 + 3];
        gb[o] = fmaxf(sG1[o] * tg + hG1[o], 0.f);
      }
      float gv[8];
#pragma unroll
      for (int j = 0; j < 8; j++) {
        float t2 = 0.f;
#pragma unroll
        for (int o = 0; o < 8; o++) t2 += gb[o] * g2[j * 8 + o];
        float gg = fmaxf(sG2[j] * t2 + hG2[j], 0.f);
        gv[j] = wt * gg;
      }
      pk.x = pack2(gv[0], gv[1]); pk.y = pack2(gv[2], gv[3]);
      pk.z = pack2(gv[4], gv[5]); pk.w = pack2(gv[6], gv[7]);
    }
    vecA[8 + k][pix] = pk;
  }

  // ---- phase 4: fagg over my 32 channels, all 9 neighbors ----
  float facc[32];
#pragma unroll
  for (int c = 0; c < 32; c++) facc[c] = 0.f;
#pragma unroll
  for (int k = 0; k < 9; k++) {
    int di = k / 3 - 1, dj = k % 3 - 1;
    int hh = h + di, ww = w + dj;
    bool inb = ((unsigned)hh < (unsigned)H_) && ((unsigned)ww < (unsigned)W_);
    if (inb) {
      int ns = hh * W_ + ww;
      float wt = ev[k] * inv;
      const float* xf = xb + (size_t)(4 + half * 32) * HW_ + ns;
#pragma unroll
      for (int c = 0; c < 32; c++) facc[c] += wt * xf[c * HW_];
    }
  }
#pragma unroll
  for (int c0 = 0; c0 < 32; c0 += 8) {
    uint4 pk;
    pk.x = pack2(facc[c0], facc[c0 + 1]);     pk.y = pack2(facc[c0 + 2], facc[c0 + 3]);
    pk.z = pack2(facc[c0 + 4], facc[c0 + 5]); pk.w = pack2(facc[c0 + 6], facc[c0 + 7]);
    vecA[(half * 32 + c0) >> 3][pix] = pk;
  }
  __syncthreads();

  // ---- GEMM: D[pixel 256][chan 64] = vecA @ w_agg^T, 8 waves (4 m x 2 n) ----
  int lane = tid & 63, wave = tid >> 6;
  int q = lane >> 4, r = lane & 15;
  int wr = wave >> 1, wc = wave & 1;

  short8 Bf[2][5];
#pragma unroll
  for (int nt = 0; nt < 2; nt++) {
    int n = wc * 32 + nt * 16 + r;
#pragma unroll
    for (int ks = 0; ks < 5; ks++) {
      int k0 = ks * 32 + q * 8;
      uint4 pk; pk.x = pk.y = pk.z = pk.w = 0u;
      if (k0 < 136) {
        float4 f0 = *reinterpret_cast<const float4*>(w_agg + n * 136 + k0);
        float4 f1 = *reinterpret_cast<const float4*>(w_agg + n * 136 + k0 + 4);
        pk.x = pack2(f0.x, f0.y); pk.y = pack2(f0.z, f0.w);
        pk.z = pack2(f1.x, f1.y); pk.w = pack2(f1.z, f1.w);
      }
      Bf[nt][ks] = *reinterpret_cast<short8*>(&pk);
    }
  }

  floatx4 acc[4][2];
#pragma unroll
  for (int m = 0; m < 4; m++)
#pragma unroll
    for (int nt = 0; nt < 2; nt++) acc[m][nt] = (floatx4){0.f, 0.f, 0.f, 0.f};

#pragma unroll
  for (int m = 0; m < 4; m++) {
    int pixm = (wr * 4 + m) * 16 + r;
    short8 Af[5];
#pragma unroll
    for (int ks = 0; ks < 5; ks++) {
      int chunk = ks * 4 + q;
      if (chunk < 17)
        Af[ks] = *reinterpret_cast<const short8*>(&vecA[chunk][pixm]);
      else
        Af[ks] = (short8){0, 0, 0, 0, 0, 0, 0, 0};
    }
#pragma unroll
    for (int nt = 0; nt < 2; nt++)
#pragma unroll
      for (int ks = 0; ks < 5; ks++)
        acc[m][nt] = __builtin_amdgcn_mfma_f32_16x16x32_bf16(Af[ks], Bf[nt][ks], acc[m][nt], 0, 0, 0);
  }

  // ---- masked abn partial sums (output stays in registers) ----
  float aS[2] = {0.f, 0.f}, aQ[2] = {0.f, 0.f};
  int s0 = p0 & (HW_ - 1);
#pragma unroll
  for (int m = 0; m < 4; m++) {
    int mt = wr * 4 + m;
    int srow = s0 + mt * 16 + q * 4;
    float4 mv = *reinterpret_cast<const float4*>(mb + srow);
    float m0 = (mv.x > 0.f) ? 1.f : 0.f, m1 = (mv.y > 0.f) ? 1.f : 0.f;
    float m2 = (mv.z > 0.f) ? 1.f : 0.f, m3 = (mv.w > 0.f) ? 1.f : 0.f;
#pragma unroll
    for (int nt = 0; nt < 2; nt++) {
      aS[nt] += acc[m][nt][0] * m0 + acc[m][nt][1] * m1 + acc[m][nt][2] * m2 + acc[m][nt][3] * m3;
      aQ[nt] += acc[m][nt][0] * acc[m][nt][0] * m0 + acc[m][nt][1] * acc[m][nt][1] * m1 +
                acc[m][nt][2] * acc[m][nt][2] * m2 + acc[m][nt][3] * acc[m][nt][3] * m3;
    }
  }

  __syncthreads();  // all vecA ds_reads done; reuse LDS for reduction
  float* rS = (float*)&vecA[0][0];   // [8 waves][2 nt][16 r]
  float* rQ = rS + 256;
#pragma unroll
  for (int nt = 0; nt < 2; nt++) {
    float v1 = aS[nt], v2 = aQ[nt];
    v1 += __shfl_xor(v1, 16); v1 += __shfl_xor(v1, 32);
    v2 += __shfl_xor(v2, 16); v2 += __shfl_xor(v2, 32);
    if (lane < 16) { rS[wave * 32 + nt * 16 + lane] = v1; rQ[wave * 32 + nt * 16 + lane] = v2; }
  }
  __syncthreads();
  if (tid < 64) {
    int c = tid;
    int wc_ = c >> 5, nt_ = (c >> 4) & 1, r_ = c & 15;
    float s1 = 0.f, s2 = 0.f;
#pragma unroll
    for (int wr_ = 0; wr_ < 4; wr_++) {
      int idx = (wr_ * 2 + wc_) * 32 + nt_ * 16 + r_;
      s1 += rS[idx]; s2 += rQ[idx];
    }
    atomicAdd(&ws[64 + c], s1);
    atomicAdd(&ws[128 + c], s2);
  }

  gridbar(bar, NBLK_F);

  // ---- Phase D: abn apply + relu + center-mask zero + direct store ----
  if (tid < 64) {
    int c = tid;
    float n0 = fmaxf(wsld(&ws[33]), 1.f);
    float mean = wsld(&ws[64 + c]) / n0;
    float var = wsld(&ws[128 + c]) / n0 - mean * mean;
    float s_ = abn_g[c] * rsqrtf(var + EPS);
    scD[c] = s_; shD[c] = abn_b[c] - mean * s_;
  }
  __syncthreads();
#pragma unroll
  for (int m = 0; m < 4; m++) {
    int mt = wr * 4 + m;
    int srow = s0 + mt * 16 + q * 4;
    float4 mv = *reinterpret_cast<const float4*>(mb + srow);
#pragma unroll
    for (int nt = 0; nt < 2; nt++) {
      int ch = wc * 32 + nt * 16 + r;
      float sc_ = scD[ch], sh_ = shD[ch];
      float4 ov;
      ov.x = (mv.x > 0.f) ? fmaxf(acc[m][nt][0] * sc_ + sh_, 0.f) : 0.f;
      ov.y = (mv.y > 0.f) ? fmaxf(acc[m][nt][1] * sc_ + sh_, 0.f) : 0.f;
      ov.z = (mv.z > 0.f) ? fmaxf(acc[m][nt][2] * sc_ + sh_, 0.f) : 0.f;
      ov.w = (mv.w > 0.f) ? fmaxf(acc[m][nt][3] * sc_ + sh_, 0.f) : 0.f;
      *reinterpret_cast<float4*>(out + ((size_t)(b * 64 + ch)) * HW_ + srow) = ov;
    }
  }
}

extern "C" void kernel_launch(void* const* d_in, const int* in_sizes, int n_in,
                              void* d_out, int out_size, void* d_ws, size_t ws_size,
                              hipStream_t stream) {
  const float* x      = (const float*)d_in[0];
  const float* mask   = (const float*)d_in[1];
  const float* w1     = (const float*)d_in[2];
  const float* bn1_g  = (const float*)d_in[3];
  const float* bn1_b  = (const float*)d_in[4];
  const float* w2     = (const float*)d_in[5];
  const float* b2     = (const float*)d_in[6];
  const float* g1     = (const float*)d_in[7];
  const float* gbn1_g = (const float*)d_in[8];
  const float* gbn1_b = (const float*)d_in[9];
  const float* g2     = (const float*)d_in[10];
  const float* gbn2_g = (const float*)d_in[11];
  const float* gbn2_b = (const float*)d_in[12];
  const float* w_agg  = (const float*)d_in[13];
  const float* abn_g  = (const float*)d_in[14];
  const float* abn_b  = (const float*)d_in[15];
  float* out = (float*)d_out;

  if (ws_size < 1024) return;
  float* wsf = (float*)d_ws;

  // zeroes stats (ws[0..191]) AND barrier state (ws[248..249])
  hipMemsetAsync(d_ws, 0, 1024, stream);
  k_stats1<<<2048, 256, 0, stream>>>(x, mask, w1, g1, wsf);
  k_stats2<<<2048, 256, 0, stream>>>(x, mask, g1, gbn1_g, gbn1_b, g2, wsf);
  k_fused<<<NBLK_F, 512, 0, stream>>>(x, mask, w1, bn1_g, bn1_b, w2, b2, g1,
                                      gbn1_g, gbn1_b, g2, gbn2_g, gbn2_b, w_agg,
                                      abn_g, abn_b, wsf, out);
}

// Round 7
// 209.854 us; speedup vs baseline: 1.7991x; 1.7991x over previous
//
#include <hip/hip_runtime.h>

#define HW_ 65536
#define W_ 1024
#define H_ 64
#define B_ 2
#define C_ 68
#define NPIX 131072
#define EPS 1e-5f
#define SCOLS 258
#define STOT (15 * SCOLS)  // 4 x-channels * 3 rows + 3 mask rows, 258 cols

typedef __attribute__((ext_vector_type(8))) short short8;
typedef __attribute__((ext_vector_type(4))) float floatx4;

__device__ __forceinline__ unsigned short f2bf(float f) {
  unsigned u = __float_as_uint(f);
  u += 0x7fffu + ((u >> 16) & 1u);
  return (unsigned short)(u >> 16);
}
__device__ __forceinline__ unsigned pack2(float a, float b) {
  return (unsigned)f2bf(a) | ((unsigned)f2bf(b) << 16);
}
__device__ __forceinline__ float wred(float v) {
  v += __shfl_xor(v, 1);  v += __shfl_xor(v, 2);  v += __shfl_xor(v, 4);
  v += __shfl_xor(v, 8);  v += __shfl_xor(v, 16); v += __shfl_xor(v, 32);
  return v;
}
__device__ __forceinline__ int swz_tile(int bid) {
  // XCD-contiguous: XCD j (= bid%8) owns tiles [j*64, j*64+64)
  return (bid & 7) * 64 + (bid >> 3);
}

// All 256 pixels of a tile share one image row h (256 | 1024). Stage the 3
// rows (h-1,h,h+1) x cols [w0-1, w0+256] of x ch0-3 and mask into LDS:
// 15*258 floats = 15.5 KB, ~STOT/NT coalesced loads per thread. OOB -> 0
// (mask=0 gates everything that must be gated; fagg gates recomputed inline).
#define XSTG(ch, row, col) stg[((ch) * 3 + (row)) * SCOLS + (col)]
#define MSTG(row, col)     stg[(12 + (row)) * SCOLS + (col)]

template <int NT>
__device__ __forceinline__ void stage_rows(const float* xb, const float* mb,
                                           int h, int w0, float* stg, int tid) {
#pragma unroll 1
  for (int i = tid; i < STOT; i += NT) {
    int seg = i / SCOLS, col = i - seg * SCOLS;
    int arr = seg / 3, row = seg - arr * 3;
    int wg = w0 - 1 + col, hg = h + row - 1;
    bool ok = ((unsigned)wg < (unsigned)W_) && ((unsigned)hg < (unsigned)H_);
    float v = 0.f;
    if (ok) v = (arr < 4) ? xb[(size_t)arr * HW_ + (hg << 10) + wg]
                          : mb[(hg << 10) + wg];
    stg[i] = v;
  }
}

// ---- K1: stats1, 2 threads/pixel (grid 1024), LDS row staging ----
__global__ __launch_bounds__(256, 4) void k_stats1(
    const float* __restrict__ x, const float* __restrict__ mask,
    const float* __restrict__ w1, const float* __restrict__ g1,
    float* __restrict__ ws) {
  __shared__ float stg[STOT];
  __shared__ float red[4][34];
  int half = blockIdx.x >> 9;
  int tile = swz_tile(blockIdx.x & 511);
  int p0 = tile * 256;
  int b = p0 >> 16, s0 = p0 & (HW_ - 1);
  int h = s0 >> 10, w0 = s0 & (W_ - 1);
  const float* xb = x + (size_t)b * C_ * HW_;
  const float* mb = mask + (size_t)b * HW_;
  stage_rows<256>(xb, mb, h, w0, stg, threadIdx.x);
  __syncthreads();

  int pix = threadIdx.x;
  float xc0 = XSTG(0, 1, 1 + pix), xc1 = XSTG(1, 1, 1 + pix);
  float xc2 = XSTG(2, 1, 1 + pix), xc3 = XSTG(3, 1, 1 + pix);

  float acc[34];
#pragma unroll
  for (int i = 0; i < 34; i++) acc[i] = 0.f;
  if (half == 0) acc[33] = (MSTG(1, 1 + pix) > 0.f) ? 1.f : 0.f;  // center mask once

  int kb = half ? 5 : 0, ke = half ? 9 : 5;
#pragma unroll
  for (int k = 0; k < 9; k++) {
    if (k < kb || k >= ke) continue;
    int row = k / 3, col = 1 + pix + (k % 3 - 1);
    float mval = MSTG(row, col);
    if (mval > 0.f) {
      float pn0 = XSTG(0, row, col) - xc0;
      float pn1 = XSTG(1, row, col) - xc1;
      float pn2 = XSTG(2, row, col) - xc2;
      float pn3 = XSTG(3, row, col) - xc3;
      acc[32] += 1.f;
#pragma unroll
      for (int o = 0; o < 8; o++) {
        float ta = pn0 * w1[o * 4] + pn1 * w1[o * 4 + 1] + pn2 * w1[o * 4 + 2] + pn3 * w1[o * 4 + 3];
        acc[o] += ta; acc[8 + o] += ta * ta;
        float tg = pn0 * g1[o * 4] + pn1 * g1[o * 4 + 1] + pn2 * g1[o * 4 + 2] + pn3 * g1[o * 4 + 3];
        acc[16 + o] += tg; acc[24 + o] += tg * tg;
      }
    }
  }
  int lane = threadIdx.x & 63, wave = threadIdx.x >> 6;
#pragma unroll
  for (int i = 0; i < 34; i++) {
    float rv = wred(acc[i]);
    if (lane == 0) red[wave][i] = rv;
  }
  __syncthreads();
  if (threadIdx.x < 34)
    atomicAdd(&ws[threadIdx.x],
              red[0][threadIdx.x] + red[1][threadIdx.x] + red[2][threadIdx.x] + red[3][threadIdx.x]);
}

// ---- K2: stats2, same structure ----
__global__ __launch_bounds__(256, 4) void k_stats2(
    const float* __restrict__ x, const float* __restrict__ mask,
    const float* __restrict__ g1, const float* __restrict__ gbn1_g,
    const float* __restrict__ gbn1_b, const float* __restrict__ g2,
    float* __restrict__ ws) {
  __shared__ float stg[STOT];
  __shared__ float red[4][16];
  __shared__ float sc[8], sh[8];
  if (threadIdx.x < 8) {
    int o = threadIdx.x;
    float n = fmaxf(ws[32], 1.f);
    float mean = ws[16 + o] / n;
    float var = ws[24 + o] / n - mean * mean;
    float s_ = gbn1_g[o] * rsqrtf(var + EPS);
    sc[o] = s_; sh[o] = gbn1_b[o] - mean * s_;
  }
  int half = blockIdx.x >> 9;
  int tile = swz_tile(blockIdx.x & 511);
  int p0 = tile * 256;
  int b = p0 >> 16, s0 = p0 & (HW_ - 1);
  int h = s0 >> 10, w0 = s0 & (W_ - 1);
  const float* xb = x + (size_t)b * C_ * HW_;
  const float* mb = mask + (size_t)b * HW_;
  stage_rows<256>(xb, mb, h, w0, stg, threadIdx.x);
  __syncthreads();

  int pix = threadIdx.x;
  float xc0 = XSTG(0, 1, 1 + pix), xc1 = XSTG(1, 1, 1 + pix);
  float xc2 = XSTG(2, 1, 1 + pix), xc3 = XSTG(3, 1, 1 + pix);

  float acc2[16];
#pragma unroll
  for (int i = 0; i < 16; i++) acc2[i] = 0.f;

  int kb = half ? 5 : 0, ke = half ? 9 : 5;
#pragma unroll
  for (int k = 0; k < 9; k++) {
    if (k < kb || k >= ke) continue;
    int row = k / 3, col = 1 + pix + (k % 3 - 1);
    float mval = MSTG(row, col);
    if (mval > 0.f) {
      float pn0 = XSTG(0, row, col) - xc0;
      float pn1 = XSTG(1, row, col) - xc1;
      float pn2 = XSTG(2, row, col) - xc2;
      float pn3 = XSTG(3, row, col) - xc3;
      float gb[8];
#pragma unroll
      for (int o = 0; o < 8; o++) {
        float tg = pn0 * g1[o * 4] + pn1 * g1[o * 4 + 1] + pn2 * g1[o * 4 + 2] + pn3 * g1[o * 4 + 3];
        gb[o] = fmaxf(sc[o] * tg + sh[o], 0.f);
      }
#pragma unroll
      for (int j = 0; j < 8; j++) {
        float t2 = 0.f;
#pragma unroll
        for (int o = 0; o < 8; o++) t2 += gb[o] * g2[j * 8 + o];
        acc2[j] += t2; acc2[8 + j] += t2 * t2;
      }
    }
  }
  int lane = threadIdx.x & 63, wave = threadIdx.x >> 6;
#pragma unroll
  for (int i = 0; i < 16; i++) {
    float rv = wred(acc2[i]);
    if (lane == 0) red[wave][i] = rv;
  }
  __syncthreads();
  if (threadIdx.x < 16)
    atomicAdd(&ws[40 + threadIdx.x],
              red[0][threadIdx.x] + red[1][threadIdx.x] + red[2][threadIdx.x] + red[3][threadIdx.x]);
}

// --------- K3: fused kernel, 512 thr / 256 pixels, staged gather + pn cache -
// half 0: neighbors k=0..4; half 1: k=5..8. fagg split by channel (32 each).
// Staging overlays vecA[0..] (bytes 0..15479); phase 3 writes vecA[8+] (bytes
// >=32768, no overlap); phase 4 writes vecA[0..7] only after the phase-1 sync,
// by which point all staging reads are done.
__global__ __launch_bounds__(512, 4) void k_fused(
    const float* __restrict__ x, const float* __restrict__ mask,
    const float* __restrict__ w1, const float* __restrict__ bn1_g,
    const float* __restrict__ bn1_b, const float* __restrict__ w2,
    const float* __restrict__ b2, const float* __restrict__ g1,
    const float* __restrict__ gbn1_g, const float* __restrict__ gbn1_b,
    const float* __restrict__ g2, const float* __restrict__ gbn2_g,
    const float* __restrict__ gbn2_b, const float* __restrict__ w_agg,
    const float* __restrict__ ws, float* __restrict__ out_pre,
    float* __restrict__ wsum) {
  __shared__ uint4 vecA[17][256];   // 69.6 KB : staging, then K-major bf16 chunks
  __shared__ float evb[9][256];     // 9 KB   : softmax logit exchange
  __shared__ float sA[8], hA[8], sG1[8], hG1[8], sG2[8], hG2[8];
  float* stg = (float*)&vecA[0][0];

  if (threadIdx.x < 24) {
    int o = threadIdx.x & 7;
    float n = fmaxf(ws[32], 1.f);
    float sum, sum2, gma, bta;
    if (threadIdx.x < 8)       { sum = ws[o];      sum2 = ws[8 + o];  gma = bn1_g[o];  bta = bn1_b[o]; }
    else if (threadIdx.x < 16) { sum = ws[16 + o]; sum2 = ws[24 + o]; gma = gbn1_g[o]; bta = gbn1_b[o]; }
    else                       { sum = ws[40 + o]; sum2 = ws[48 + o]; gma = gbn2_g[o]; bta = gbn2_b[o]; }
    float mean = sum / n, var = sum2 / n - mean * mean;
    float s_ = gma * rsqrtf(var + EPS);
    float sft = bta - mean * s_;
    if (threadIdx.x < 8)       { sA[o] = s_;  hA[o] = sft; }
    else if (threadIdx.x < 16) { sG1[o] = s_; hG1[o] = sft; }
    else                       { sG2[o] = s_; hG2[o] = sft; }
  }

  int tid = threadIdx.x;
  int half = tid >> 8;      // 0: k 0..4, 1: k 5..8  (wave-uniform)
  int pix = tid & 255;
  int tile = swz_tile(blockIdx.x);
  int p0 = tile * 256;
  int b = p0 >> 16, s0 = p0 & (HW_ - 1);
  int h = s0 >> 10, w0 = s0 & (W_ - 1);
  const float* xb = x + (size_t)b * C_ * HW_;
  const float* mb = mask + (size_t)b * HW_;
  stage_rows<512>(xb, mb, h, w0, stg, tid);
  __syncthreads();

  float xc0 = XSTG(0, 1, 1 + pix), xc1 = XSTG(1, 1, 1 + pix);
  float xc2 = XSTG(2, 1, 1 + pix), xc3 = XSTG(3, 1, 1 + pix);
  float b2v = b2[0];

  // ---- phase 1: softmax logits for my neighbors; cache pn in registers ----
  float pnc[5][4];
  unsigned mbits = 0u;
  int kb = half ? 5 : 0, ke = half ? 9 : 5;
#pragma unroll
  for (int k = 0; k < 9; k++) {
    if (k < kb || k >= ke) continue;
    int j = k - kb;
    int row = k / 3, col = 1 + pix + (k % 3 - 1);
    float mval = MSTG(row, col);
    float wp = 0.f;
    pnc[j][0] = 0.f; pnc[j][1] = 0.f; pnc[j][2] = 0.f; pnc[j][3] = 0.f;
    if (mval > 0.f) {
      mbits |= (1u << k);
      pnc[j][0] = XSTG(0, row, col) - xc0;
      pnc[j][1] = XSTG(1, row, col) - xc1;
      pnc[j][2] = XSTG(2, row, col) - xc2;
      pnc[j][3] = XSTG(3, row, col) - xc3;
      float accw = 0.f;
#pragma unroll
      for (int o = 0; o < 8; o++) {
        float ta = pnc[j][0] * w1[o * 4] + pnc[j][1] * w1[o * 4 + 1] +
                   pnc[j][2] * w1[o * 4 + 2] + pnc[j][3] * w1[o * 4 + 3];
        accw += fmaxf(sA[o] * ta + hA[o], 0.f) * w2[o];
      }
      wp = accw + b2v;
    }
    evb[k][pix] = wp;
  }
  __syncthreads();   // evb ready; also: all staging reads done before phase 4

  // ---- phase 2: both halves compute identical softmax weights ----
  float ev[9];
  float mx = -1e30f;
#pragma unroll
  for (int k = 0; k < 9; k++) { ev[k] = evb[k][pix]; mx = fmaxf(mx, ev[k]); }
  float den = 0.f;
#pragma unroll
  for (int k = 0; k < 9; k++) { ev[k] = __expf(ev[k] - mx); den += ev[k]; }
  float inv = 1.f / den;

  // ---- phase 3: g-vec for my neighbors (register pn, zero loads) ----
#pragma unroll
  for (int k = 0; k < 9; k++) {
    if (k < kb || k >= ke) continue;
    int j = k - kb;
    uint4 pk; pk.x = pk.y = pk.z = pk.w = 0u;
    if ((mbits >> k) & 1u) {
      float wt = ev[k] * inv;
      float gb[8];
#pragma unroll
      for (int o = 0; o < 8; o++) {
        float tg = pnc[j][0] * g1[o * 4] + pnc[j][1] * g1[o * 4 + 1] +
                   pnc[j][2] * g1[o * 4 + 2] + pnc[j][3] * g1[o * 4 + 3];
        gb[o] = fmaxf(sG1[o] * tg + hG1[o], 0.f);
      }
      float gv[8];
#pragma unroll
      for (int j2 = 0; j2 < 8; j2++) {
        float t2 = 0.f;
#pragma unroll
        for (int o = 0; o < 8; o++) t2 += gb[o] * g2[j2 * 8 + o];
        float gg = fmaxf(sG2[j2] * t2 + hG2[j2], 0.f);
        gv[j2] = wt * gg;
      }
      pk.x = pack2(gv[0], gv[1]); pk.y = pack2(gv[2], gv[3]);
      pk.z = pack2(gv[4], gv[5]); pk.w = pack2(gv[6], gv[7]);
    }
    vecA[8 + k][pix] = pk;
  }

  // ---- phase 4: fagg over my 32 channels, all 9 neighbors (coalesced) ----
  float facc[32];
#pragma unroll
  for (int c = 0; c < 32; c++) facc[c] = 0.f;
#pragma unroll
  for (int k = 0; k < 9; k++) {
    int di = k / 3 - 1, dj = k % 3 - 1;
    int hh = h + di, ww = w0 + pix + dj;
    bool inb = ((unsigned)hh < (unsigned)H_) && ((unsigned)ww < (unsigned)W_);
    if (inb) {
      int ns = (hh << 10) + ww;
      float wt = ev[k] * inv;
      const float* xf = xb + (size_t)(4 + half * 32) * HW_ + ns;
#pragma unroll
      for (int c = 0; c < 32; c++) facc[c] += wt * xf[(size_t)c * HW_];
    }
  }
#pragma unroll
  for (int c0 = 0; c0 < 32; c0 += 8) {
    uint4 pk;
    pk.x = pack2(facc[c0], facc[c0 + 1]);     pk.y = pack2(facc[c0 + 2], facc[c0 + 3]);
    pk.z = pack2(facc[c0 + 4], facc[c0 + 5]); pk.w = pack2(facc[c0 + 6], facc[c0 + 7]);
    vecA[(half * 32 + c0) >> 3][pix] = pk;
  }
  __syncthreads();

  // ---- GEMM: D[pixel 256][chan 64] = vecA @ w_agg^T, 8 waves (4 m x 2 n) ----
  int lane = tid & 63, wave = tid >> 6;
  int q = lane >> 4, r = lane & 15;
  int wr = wave >> 1, wc = wave & 1;

  short8 Bf[2][5];
#pragma unroll
  for (int nt = 0; nt < 2; nt++) {
    int n = wc * 32 + nt * 16 + r;
#pragma unroll
    for (int ks = 0; ks < 5; ks++) {
      int k0 = ks * 32 + q * 8;
      uint4 pk; pk.x = pk.y = pk.z = pk.w = 0u;
      if (k0 < 136) {
        float4 f0 = *reinterpret_cast<const float4*>(w_agg + n * 136 + k0);
        float4 f1 = *reinterpret_cast<const float4*>(w_agg + n * 136 + k0 + 4);
        pk.x = pack2(f0.x, f0.y); pk.y = pack2(f0.z, f0.w);
        pk.z = pack2(f1.x, f1.y); pk.w = pack2(f1.z, f1.w);
      }
      Bf[nt][ks] = *reinterpret_cast<short8*>(&pk);
    }
  }

  floatx4 acc[4][2];
#pragma unroll
  for (int m = 0; m < 4; m++)
#pragma unroll
    for (int nt = 0; nt < 2; nt++) acc[m][nt] = (floatx4){0.f, 0.f, 0.f, 0.f};

#pragma unroll
  for (int m = 0; m < 4; m++) {
    int pixm = (wr * 4 + m) * 16 + r;
    short8 Af[5];
#pragma unroll
    for (int ks = 0; ks < 5; ks++) {
      int chunk = ks * 4 + q;
      if (chunk < 17)
        Af[ks] = *reinterpret_cast<const short8*>(&vecA[chunk][pixm]);
      else
        Af[ks] = (short8){0, 0, 0, 0, 0, 0, 0, 0};
    }
#pragma unroll
    for (int nt = 0; nt < 2; nt++)
#pragma unroll
      for (int ks = 0; ks < 5; ks++)
        acc[m][nt] = __builtin_amdgcn_mfma_f32_16x16x32_bf16(Af[ks], Bf[nt][ks], acc[m][nt], 0, 0, 0);
  }

  // ---- store + masked abn partial sums ----
  float aS[2] = {0.f, 0.f}, aQ[2] = {0.f, 0.f};
#pragma unroll
  for (int m = 0; m < 4; m++) {
    int mt = wr * 4 + m;
    int srow = s0 + mt * 16 + q * 4;
    float4 mv = *reinterpret_cast<const float4*>(mb + srow);
    float m0 = (mv.x > 0.f) ? 1.f : 0.f, m1 = (mv.y > 0.f) ? 1.f : 0.f;
    float m2 = (mv.z > 0.f) ? 1.f : 0.f, m3 = (mv.w > 0.f) ? 1.f : 0.f;
#pragma unroll
    for (int nt = 0; nt < 2; nt++) {
      int ch = wc * 32 + nt * 16 + r;
      float4 ov;
      ov.x = acc[m][nt][0]; ov.y = acc[m][nt][1];
      ov.z = acc[m][nt][2]; ov.w = acc[m][nt][3];
      aS[nt] += ov.x * m0 + ov.y * m1 + ov.z * m2 + ov.w * m3;
      aQ[nt] += ov.x * ov.x * m0 + ov.y * ov.y * m1 + ov.z * ov.z * m2 + ov.w * ov.w * m3;
      *reinterpret_cast<float4*>(out_pre + ((size_t)(b * 64 + ch)) * HW_ + srow) = ov;
    }
  }

  __syncthreads();  // all vecA ds_reads done; reuse LDS for reduction
  float* rS = (float*)&vecA[0][0];   // [8 waves][2 nt][16 r]
  float* rQ = rS + 256;
#pragma unroll
  for (int nt = 0; nt < 2; nt++) {
    float v1 = aS[nt], v2 = aQ[nt];
    v1 += __shfl_xor(v1, 16); v1 += __shfl_xor(v1, 32);
    v2 += __shfl_xor(v2, 16); v2 += __shfl_xor(v2, 32);
    if (lane < 16) { rS[wave * 32 + nt * 16 + lane] = v1; rQ[wave * 32 + nt * 16 + lane] = v2; }
  }
  __syncthreads();
  if (tid < 64) {
    int c = tid;
    int wc_ = c >> 5, nt_ = (c >> 4) & 1, r_ = c & 15;
    float s1 = 0.f, s2 = 0.f;
#pragma unroll
    for (int wr_ = 0; wr_ < 4; wr_++) {
      int idx = (wr_ * 2 + wc_) * 32 + nt_ * 16 + r_;
      s1 += rS[idx]; s2 += rQ[idx];
    }
    atomicAdd(&wsum[64 + c], s1);
    atomicAdd(&wsum[128 + c], s2);
  }
}

// ---------------- K4: abn apply + relu + center-mask zero -------------------
__global__ __launch_bounds__(256) void k_final(
    const float* __restrict__ out_pre, const float* __restrict__ mask,
    const float* __restrict__ abn_g, const float* __restrict__ abn_b,
    const float* __restrict__ ws, float* __restrict__ out) {
  __shared__ float sc[64], sh[64];
  if (threadIdx.x < 64) {
    int c = threadIdx.x;
    float n0 = fmaxf(ws[33], 1.f);
    float mean = ws[64 + c] / n0;
    float var = ws[128 + c] / n0 - mean * mean;
    float s_ = abn_g[c] * rsqrtf(var + EPS);
    sc[c] = s_; sh[c] = abn_b[c] - mean * s_;
  }
  __syncthreads();
  int i4 = (blockIdx.x * 256 + threadIdx.x) * 4;
  if (i4 >= B_ * 64 * HW_) return;
  int c = (i4 >> 16) & 63;
  int b = i4 >> 22;
  int s = i4 & (HW_ - 1);
  float4 v = *reinterpret_cast<const float4*>(out_pre + i4);
  float4 m = *reinterpret_cast<const float4*>(mask + (size_t)b * HW_ + s);
  float4 o;
  o.x = (m.x > 0.f) ? fmaxf(v.x * sc[c] + sh[c], 0.f) : 0.f;
  o.y = (m.y > 0.f) ? fmaxf(v.y * sc[c] + sh[c], 0.f) : 0.f;
  o.z = (m.z > 0.f) ? fmaxf(v.z * sc[c] + sh[c], 0.f) : 0.f;
  o.w = (m.w > 0.f) ? fmaxf(v.w * sc[c] + sh[c], 0.f) : 0.f;
  *reinterpret_cast<float4*>(out + i4) = o;
}

extern "C" void kernel_launch(void* const* d_in, const int* in_sizes, int n_in,
                              void* d_out, int out_size, void* d_ws, size_t ws_size,
                              hipStream_t stream) {
  const float* x      = (const float*)d_in[0];
  const float* mask   = (const float*)d_in[1];
  const float* w1     = (const float*)d_in[2];
  const float* bn1_g  = (const float*)d_in[3];
  const float* bn1_b  = (const float*)d_in[4];
  const float* w2     = (const float*)d_in[5];
  const float* b2     = (const float*)d_in[6];
  const float* g1     = (const float*)d_in[7];
  const float* gbn1_g = (const float*)d_in[8];
  const float* gbn1_b = (const float*)d_in[9];
  const float* g2     = (const float*)d_in[10];
  const float* gbn2_g = (const float*)d_in[11];
  const float* gbn2_b = (const float*)d_in[12];
  const float* w_agg  = (const float*)d_in[13];
  const float* abn_g  = (const float*)d_in[14];
  const float* abn_b  = (const float*)d_in[15];
  float* out = (float*)d_out;

  size_t need = 1024 + (size_t)NPIX * 64 * 4;
  if (ws_size < need) return;

  float* wsf = (float*)d_ws;
  float* out_pre = (float*)((char*)d_ws + 1024);

  hipMemsetAsync(d_ws, 0, 1024, stream);
  k_stats1<<<1024, 256, 0, stream>>>(x, mask, w1, g1, wsf);
  k_stats2<<<1024, 256, 0, stream>>>(x, mask, g1, gbn1_g, gbn1_b, g2, wsf);
  k_fused<<<512, 512, 0, stream>>>(x, mask, w1, bn1_g, bn1_b, w2, b2, g1,
                                   gbn1_g, gbn1_b, g2, gbn2_g, gbn2_b, w_agg,
                                   wsf, out_pre, wsf);
  k_final<<<8192, 256, 0, stream>>>(out_pre, mask, abn_g, abn_b, wsf, out);
}

// Round 8
// 190.144 us; speedup vs baseline: 1.9856x; 1.1037x over previous
//
#include <hip/hip_runtime.h>

#define HW_ 65536
#define W_ 1024
#define H_ 64
#define B_ 2
#define C_ 68
#define NPIX 131072
#define EPS 1e-5f
#define SCOLS 258
#define STOT (15 * SCOLS)  // 4 x-channels * 3 rows + 3 mask rows, 258 cols

typedef __attribute__((ext_vector_type(8))) short short8;
typedef __attribute__((ext_vector_type(4))) float floatx4;

__device__ __forceinline__ unsigned short f2bf(float f) {
  unsigned u = __float_as_uint(f);
  u += 0x7fffu + ((u >> 16) & 1u);
  return (unsigned short)(u >> 16);
}
__device__ __forceinline__ unsigned pack2(float a, float b) {
  return (unsigned)f2bf(a) | ((unsigned)f2bf(b) << 16);
}
__device__ __forceinline__ float bf2f(unsigned u) {
  return __uint_as_float(u << 16);
}
__device__ __forceinline__ float wred(float v) {
  v += __shfl_xor(v, 1);  v += __shfl_xor(v, 2);  v += __shfl_xor(v, 4);
  v += __shfl_xor(v, 8);  v += __shfl_xor(v, 16); v += __shfl_xor(v, 32);
  return v;
}
__device__ __forceinline__ int swz_tile(int bid) {
  // XCD-contiguous: XCD j (= bid%8) owns tiles [j*64, j*64+64)
  return (bid & 7) * 64 + (bid >> 3);
}

// Stage 3 rows x cols [w0-1, w0+256] of x ch0-3 and mask into LDS (15.5 KB).
#define XSTG(ch, row, col) stg[((ch) * 3 + (row)) * SCOLS + (col)]
#define MSTG(row, col)     stg[(12 + (row)) * SCOLS + (col)]

template <int NT>
__device__ __forceinline__ void stage_rows(const float* xb, const float* mb,
                                           int h, int w0, float* stg, int tid) {
#pragma unroll 1
  for (int i = tid; i < STOT; i += NT) {
    int seg = i / SCOLS, col = i - seg * SCOLS;
    int arr = seg / 3, row = seg - arr * 3;
    int wg = w0 - 1 + col, hg = h + row - 1;
    bool ok = ((unsigned)wg < (unsigned)W_) && ((unsigned)hg < (unsigned)H_);
    float v = 0.f;
    if (ok) v = (arr < 4) ? xb[(size_t)arr * HW_ + (hg << 10) + wg]
                          : mb[(hg << 10) + wg];
    stg[i] = v;
  }
}

// ---- K1: stats1 via moment matrix. ws[0..3]=S=sum(pn), ws[4..13]=M=sum(pn pn^T)
// packed (00,01,02,03,11,12,13,22,23,33), ws[14]=masked count, ws[15]=center count.
// Consumers reconstruct: mean_o = w_o.S/n ; var_o = w_o^T M w_o / n - mean^2.
__global__ __launch_bounds__(256, 4) void k_stats1(
    const float* __restrict__ x, const float* __restrict__ mask,
    float* __restrict__ ws) {
  __shared__ float stg[STOT];
  __shared__ float red[4][16];
  int tile = swz_tile(blockIdx.x);
  int p0 = tile * 256;
  int b = p0 >> 16, s0 = p0 & (HW_ - 1);
  int h = s0 >> 10, w0 = s0 & (W_ - 1);
  const float* xb = x + (size_t)b * C_ * HW_;
  const float* mb = mask + (size_t)b * HW_;
  stage_rows<256>(xb, mb, h, w0, stg, threadIdx.x);
  __syncthreads();

  int pix = threadIdx.x;
  float xc0 = XSTG(0, 1, 1 + pix), xc1 = XSTG(1, 1, 1 + pix);
  float xc2 = XSTG(2, 1, 1 + pix), xc3 = XSTG(3, 1, 1 + pix);

  float a[16];
#pragma unroll
  for (int i = 0; i < 16; i++) a[i] = 0.f;
  a[15] = (MSTG(1, 1 + pix) > 0.f) ? 1.f : 0.f;

#pragma unroll
  for (int k = 0; k < 9; k++) {
    int row = k / 3, col = 1 + pix + (k % 3 - 1);
    float mval = MSTG(row, col);
    if (mval > 0.f) {
      float pn0 = XSTG(0, row, col) - xc0;
      float pn1 = XSTG(1, row, col) - xc1;
      float pn2 = XSTG(2, row, col) - xc2;
      float pn3 = XSTG(3, row, col) - xc3;
      a[14] += 1.f;
      a[0] += pn0; a[1] += pn1; a[2] += pn2; a[3] += pn3;
      a[4] += pn0 * pn0; a[5] += pn0 * pn1; a[6] += pn0 * pn2; a[7] += pn0 * pn3;
      a[8] += pn1 * pn1; a[9] += pn1 * pn2; a[10] += pn1 * pn3;
      a[11] += pn2 * pn2; a[12] += pn2 * pn3; a[13] += pn3 * pn3;
    }
  }
  int lane = threadIdx.x & 63, wave = threadIdx.x >> 6;
#pragma unroll
  for (int i = 0; i < 16; i++) {
    float rv = wred(a[i]);
    if (lane == 0) red[wave][i] = rv;
  }
  __syncthreads();
  if (threadIdx.x < 16)
    atomicAdd(&ws[threadIdx.x],
              red[0][threadIdx.x] + red[1][threadIdx.x] + red[2][threadIdx.x] + red[3][threadIdx.x]);
}

// ---- K2: stats2, 2 threads/pixel (grid 1024); gbn1 scale from S/M ----
__global__ __launch_bounds__(256, 4) void k_stats2(
    const float* __restrict__ x, const float* __restrict__ mask,
    const float* __restrict__ g1, const float* __restrict__ gbn1_g,
    const float* __restrict__ gbn1_b, const float* __restrict__ g2,
    float* __restrict__ ws) {
  __shared__ float stg[STOT];
  __shared__ float red[4][16];
  __shared__ float sc[8], sh[8];
  if (threadIdx.x < 8) {
    int o = threadIdx.x;
    float a0 = g1[o * 4], a1 = g1[o * 4 + 1], a2 = g1[o * 4 + 2], a3 = g1[o * 4 + 3];
    float n = fmaxf(ws[14], 1.f);
    float mean = (a0 * ws[0] + a1 * ws[1] + a2 * ws[2] + a3 * ws[3]) / n;
    float q = a0 * a0 * ws[4] + a1 * a1 * ws[8] + a2 * a2 * ws[11] + a3 * a3 * ws[13]
            + 2.f * (a0 * a1 * ws[5] + a0 * a2 * ws[6] + a0 * a3 * ws[7]
                   + a1 * a2 * ws[9] + a1 * a3 * ws[10] + a2 * a3 * ws[12]);
    float var = q / n - mean * mean;
    float s_ = gbn1_g[o] * rsqrtf(var + EPS);
    sc[o] = s_; sh[o] = gbn1_b[o] - mean * s_;
  }
  int half = blockIdx.x >> 9;
  int tile = swz_tile(blockIdx.x & 511);
  int p0 = tile * 256;
  int b = p0 >> 16, s0 = p0 & (HW_ - 1);
  int h = s0 >> 10, w0 = s0 & (W_ - 1);
  const float* xb = x + (size_t)b * C_ * HW_;
  const float* mb = mask + (size_t)b * HW_;
  stage_rows<256>(xb, mb, h, w0, stg, threadIdx.x);
  __syncthreads();

  int pix = threadIdx.x;
  float xc0 = XSTG(0, 1, 1 + pix), xc1 = XSTG(1, 1, 1 + pix);
  float xc2 = XSTG(2, 1, 1 + pix), xc3 = XSTG(3, 1, 1 + pix);

  float acc2[16];
#pragma unroll
  for (int i = 0; i < 16; i++) acc2[i] = 0.f;

  int kb = half ? 5 : 0, ke = half ? 9 : 5;
#pragma unroll
  for (int k = 0; k < 9; k++) {
    if (k < kb || k >= ke) continue;
    int row = k / 3, col = 1 + pix + (k % 3 - 1);
    float mval = MSTG(row, col);
    if (mval > 0.f) {
      float pn0 = XSTG(0, row, col) - xc0;
      float pn1 = XSTG(1, row, col) - xc1;
      float pn2 = XSTG(2, row, col) - xc2;
      float pn3 = XSTG(3, row, col) - xc3;
      float gb[8];
#pragma unroll
      for (int o = 0; o < 8; o++) {
        float tg = pn0 * g1[o * 4] + pn1 * g1[o * 4 + 1] + pn2 * g1[o * 4 + 2] + pn3 * g1[o * 4 + 3];
        gb[o] = fmaxf(sc[o] * tg + sh[o], 0.f);
      }
#pragma unroll
      for (int j = 0; j < 8; j++) {
        float t2 = 0.f;
#pragma unroll
        for (int o = 0; o < 8; o++) t2 += gb[o] * g2[j * 8 + o];
        acc2[j] += t2; acc2[8 + j] += t2 * t2;
      }
    }
  }
  int lane = threadIdx.x & 63, wave = threadIdx.x >> 6;
#pragma unroll
  for (int i = 0; i < 16; i++) {
    float rv = wred(acc2[i]);
    if (lane == 0) red[wave][i] = rv;
  }
  __syncthreads();
  if (threadIdx.x < 16)
    atomicAdd(&ws[40 + threadIdx.x],
              red[0][threadIdx.x] + red[1][threadIdx.x] + red[2][threadIdx.x] + red[3][threadIdx.x]);
}

// --------- K3: fused kernel, 512 thr / 256 pixels; bf16 out_pre -------------
__global__ __launch_bounds__(512, 4) void k_fused(
    const float* __restrict__ x, const float* __restrict__ mask,
    const float* __restrict__ w1, const float* __restrict__ bn1_g,
    const float* __restrict__ bn1_b, const float* __restrict__ w2,
    const float* __restrict__ b2, const float* __restrict__ g1,
    const float* __restrict__ gbn1_g, const float* __restrict__ gbn1_b,
    const float* __restrict__ g2, const float* __restrict__ gbn2_g,
    const float* __restrict__ gbn2_b, const float* __restrict__ w_agg,
    const float* __restrict__ ws, unsigned short* __restrict__ out_pre,
    float* __restrict__ wsum) {
  __shared__ uint4 vecA[17][256];   // 69.6 KB : staging, then K-major bf16 chunks
  __shared__ float evb[9][256];     // 9 KB   : softmax logit exchange
  __shared__ float sA[8], hA[8], sG1[8], hG1[8], sG2[8], hG2[8];
  float* stg = (float*)&vecA[0][0];

  if (threadIdx.x < 16) {
    int o = threadIdx.x & 7;
    const float* wv = (threadIdx.x < 8) ? w1 : g1;
    float a0 = wv[o * 4], a1 = wv[o * 4 + 1], a2 = wv[o * 4 + 2], a3 = wv[o * 4 + 3];
    float n = fmaxf(ws[14], 1.f);
    float mean = (a0 * ws[0] + a1 * ws[1] + a2 * ws[2] + a3 * ws[3]) / n;
    float q = a0 * a0 * ws[4] + a1 * a1 * ws[8] + a2 * a2 * ws[11] + a3 * a3 * ws[13]
            + 2.f * (a0 * a1 * ws[5] + a0 * a2 * ws[6] + a0 * a3 * ws[7]
                   + a1 * a2 * ws[9] + a1 * a3 * ws[10] + a2 * a3 * ws[12]);
    float var = q / n - mean * mean;
    float gma = (threadIdx.x < 8) ? bn1_g[o] : gbn1_g[o];
    float bta = (threadIdx.x < 8) ? bn1_b[o] : gbn1_b[o];
    float s_ = gma * rsqrtf(var + EPS);
    float sft = bta - mean * s_;
    if (threadIdx.x < 8) { sA[o] = s_;  hA[o] = sft; }
    else                 { sG1[o] = s_; hG1[o] = sft; }
  } else if (threadIdx.x < 24) {
    int o = threadIdx.x & 7;
    float n = fmaxf(ws[14], 1.f);
    float mean = ws[40 + o] / n, var = ws[48 + o] / n - mean * mean;
    float s_ = gbn2_g[o] * rsqrtf(var + EPS);
    sG2[o] = s_; hG2[o] = gbn2_b[o] - mean * s_;
  }

  int tid = threadIdx.x;
  int half = tid >> 8;      // 0: k 0..4, 1: k 5..8  (wave-uniform)
  int pix = tid & 255;
  int tile = swz_tile(blockIdx.x);
  int p0 = tile * 256;
  int b = p0 >> 16, s0 = p0 & (HW_ - 1);
  int h = s0 >> 10, w0 = s0 & (W_ - 1);
  const float* xb = x + (size_t)b * C_ * HW_;
  const float* mb = mask + (size_t)b * HW_;
  stage_rows<512>(xb, mb, h, w0, stg, tid);
  __syncthreads();

  float xc0 = XSTG(0, 1, 1 + pix), xc1 = XSTG(1, 1, 1 + pix);
  float xc2 = XSTG(2, 1, 1 + pix), xc3 = XSTG(3, 1, 1 + pix);
  float b2v = b2[0];

  // ---- phase 1: softmax logits for my neighbors; cache pn in registers ----
  float pnc[5][4];
  unsigned mbits = 0u;
  int kb = half ? 5 : 0, ke = half ? 9 : 5;
#pragma unroll
  for (int k = 0; k < 9; k++) {
    if (k < kb || k >= ke) continue;
    int j = k - kb;
    int row = k / 3, col = 1 + pix + (k % 3 - 1);
    float mval = MSTG(row, col);
    float wp = 0.f;
    pnc[j][0] = 0.f; pnc[j][1] = 0.f; pnc[j][2] = 0.f; pnc[j][3] = 0.f;
    if (mval > 0.f) {
      mbits |= (1u << k);
      pnc[j][0] = XSTG(0, row, col) - xc0;
      pnc[j][1] = XSTG(1, row, col) - xc1;
      pnc[j][2] = XSTG(2, row, col) - xc2;
      pnc[j][3] = XSTG(3, row, col) - xc3;
      float accw = 0.f;
#pragma unroll
      for (int o = 0; o < 8; o++) {
        float ta = pnc[j][0] * w1[o * 4] + pnc[j][1] * w1[o * 4 + 1] +
                   pnc[j][2] * w1[o * 4 + 2] + pnc[j][3] * w1[o * 4 + 3];
        accw += fmaxf(sA[o] * ta + hA[o], 0.f) * w2[o];
      }
      wp = accw + b2v;
    }
    evb[k][pix] = wp;
  }
  __syncthreads();   // evb ready; staging reads done before phase-4 overwrite

  // ---- phase 2: both halves compute identical softmax weights ----
  float ev[9];
  float mx = -1e30f;
#pragma unroll
  for (int k = 0; k < 9; k++) { ev[k] = evb[k][pix]; mx = fmaxf(mx, ev[k]); }
  float den = 0.f;
#pragma unroll
  for (int k = 0; k < 9; k++) { ev[k] = __expf(ev[k] - mx); den += ev[k]; }
  float inv = 1.f / den;

  // ---- phase 3: g-vec for my neighbors (register pn, zero loads) ----
#pragma unroll
  for (int k = 0; k < 9; k++) {
    if (k < kb || k >= ke) continue;
    int j = k - kb;
    uint4 pk; pk.x = pk.y = pk.z = pk.w = 0u;
    if ((mbits >> k) & 1u) {
      float wt = ev[k] * inv;
      float gb[8];
#pragma unroll
      for (int o = 0; o < 8; o++) {
        float tg = pnc[j][0] * g1[o * 4] + pnc[j][1] * g1[o * 4 + 1] +
                   pnc[j][2] * g1[o * 4 + 2] + pnc[j][3] * g1[o * 4 + 3];
        gb[o] = fmaxf(sG1[o] * tg + hG1[o], 0.f);
      }
      float gv[8];
#pragma unroll
      for (int j2 = 0; j2 < 8; j2++) {
        float t2 = 0.f;
#pragma unroll
        for (int o = 0; o < 8; o++) t2 += gb[o] * g2[j2 * 8 + o];
        float gg = fmaxf(sG2[j2] * t2 + hG2[j2], 0.f);
        gv[j2] = wt * gg;
      }
      pk.x = pack2(gv[0], gv[1]); pk.y = pack2(gv[2], gv[3]);
      pk.z = pack2(gv[4], gv[5]); pk.w = pack2(gv[6], gv[7]);
    }
    vecA[8 + k][pix] = pk;
  }

  // ---- phase 4: fagg over my 32 channels, all 9 neighbors (coalesced) ----
  float facc[32];
#pragma unroll
  for (int c = 0; c < 32; c++) facc[c] = 0.f;
#pragma unroll
  for (int k = 0; k < 9; k++) {
    int di = k / 3 - 1, dj = k % 3 - 1;
    int hh = h + di, ww = w0 + pix + dj;
    bool inb = ((unsigned)hh < (unsigned)H_) && ((unsigned)ww < (unsigned)W_);
    if (inb) {
      int ns = (hh << 10) + ww;
      float wt = ev[k] * inv;
      const float* xf = xb + (size_t)(4 + half * 32) * HW_ + ns;
#pragma unroll
      for (int c = 0; c < 32; c++) facc[c] += wt * xf[(size_t)c * HW_];
    }
  }
#pragma unroll
  for (int c0 = 0; c0 < 32; c0 += 8) {
    uint4 pk;
    pk.x = pack2(facc[c0], facc[c0 + 1]);     pk.y = pack2(facc[c0 + 2], facc[c0 + 3]);
    pk.z = pack2(facc[c0 + 4], facc[c0 + 5]); pk.w = pack2(facc[c0 + 6], facc[c0 + 7]);
    vecA[(half * 32 + c0) >> 3][pix] = pk;
  }
  __syncthreads();

  // ---- GEMM: D[pixel 256][chan 64] = vecA @ w_agg^T, 8 waves (4 m x 2 n) ----
  int lane = tid & 63, wave = tid >> 6;
  int q = lane >> 4, r = lane & 15;
  int wr = wave >> 1, wc = wave & 1;

  short8 Bf[2][5];
#pragma unroll
  for (int nt = 0; nt < 2; nt++) {
    int n = wc * 32 + nt * 16 + r;
#pragma unroll
    for (int ks = 0; ks < 5; ks++) {
      int k0 = ks * 32 + q * 8;
      uint4 pk; pk.x = pk.y = pk.z = pk.w = 0u;
      if (k0 < 136) {
        float4 f0 = *reinterpret_cast<const float4*>(w_agg + n * 136 + k0);
        float4 f1 = *reinterpret_cast<const float4*>(w_agg + n * 136 + k0 + 4);
        pk.x = pack2(f0.x, f0.y); pk.y = pack2(f0.z, f0.w);
        pk.z = pack2(f1.x, f1.y); pk.w = pack2(f1.z, f1.w);
      }
      Bf[nt][ks] = *reinterpret_cast<short8*>(&pk);
    }
  }

  floatx4 acc[4][2];
#pragma unroll
  for (int m = 0; m < 4; m++)
#pragma unroll
    for (int nt = 0; nt < 2; nt++) acc[m][nt] = (floatx4){0.f, 0.f, 0.f, 0.f};

#pragma unroll
  for (int m = 0; m < 4; m++) {
    int pixm = (wr * 4 + m) * 16 + r;
    short8 Af[5];
#pragma unroll
    for (int ks = 0; ks < 5; ks++) {
      int chunk = ks * 4 + q;
      if (chunk < 17)
        Af[ks] = *reinterpret_cast<const short8*>(&vecA[chunk][pixm]);
      else
        Af[ks] = (short8){0, 0, 0, 0, 0, 0, 0, 0};
    }
#pragma unroll
    for (int nt = 0; nt < 2; nt++)
#pragma unroll
      for (int ks = 0; ks < 5; ks++)
        acc[m][nt] = __builtin_amdgcn_mfma_f32_16x16x32_bf16(Af[ks], Bf[nt][ks], acc[m][nt], 0, 0, 0);
  }

  // ---- store (bf16) + masked abn partial sums (from exact f32) ----
  float aS[2] = {0.f, 0.f}, aQ[2] = {0.f, 0.f};
#pragma unroll
  for (int m = 0; m < 4; m++) {
    int mt = wr * 4 + m;
    int srow = s0 + mt * 16 + q * 4;
    float4 mv = *reinterpret_cast<const float4*>(mb + srow);
    float m0 = (mv.x > 0.f) ? 1.f : 0.f, m1 = (mv.y > 0.f) ? 1.f : 0.f;
    float m2 = (mv.z > 0.f) ? 1.f : 0.f, m3 = (mv.w > 0.f) ? 1.f : 0.f;
#pragma unroll
    for (int nt = 0; nt < 2; nt++) {
      int ch = wc * 32 + nt * 16 + r;
      aS[nt] += acc[m][nt][0] * m0 + acc[m][nt][1] * m1 + acc[m][nt][2] * m2 + acc[m][nt][3] * m3;
      aQ[nt] += acc[m][nt][0] * acc[m][nt][0] * m0 + acc[m][nt][1] * acc[m][nt][1] * m1 +
                acc[m][nt][2] * acc[m][nt][2] * m2 + acc[m][nt][3] * acc[m][nt][3] * m3;
      uint2 st;
      st.x = pack2(acc[m][nt][0], acc[m][nt][1]);
      st.y = pack2(acc[m][nt][2], acc[m][nt][3]);
      *reinterpret_cast<uint2*>(out_pre + ((size_t)(b * 64 + ch)) * HW_ + srow) = st;
    }
  }

  __syncthreads();  // all vecA ds_reads done; reuse LDS for reduction
  float* rS = (float*)&vecA[0][0];   // [8 waves][2 nt][16 r]
  float* rQ = rS + 256;
#pragma unroll
  for (int nt = 0; nt < 2; nt++) {
    float v1 = aS[nt], v2 = aQ[nt];
    v1 += __shfl_xor(v1, 16); v1 += __shfl_xor(v1, 32);
    v2 += __shfl_xor(v2, 16); v2 += __shfl_xor(v2, 32);
    if (lane < 16) { rS[wave * 32 + nt * 16 + lane] = v1; rQ[wave * 32 + nt * 16 + lane] = v2; }
  }
  __syncthreads();
  if (tid < 64) {
    int c = tid;
    int wc_ = c >> 5, nt_ = (c >> 4) & 1, r_ = c & 15;
    float s1 = 0.f, s2 = 0.f;
#pragma unroll
    for (int wr_ = 0; wr_ < 4; wr_++) {
      int idx = (wr_ * 2 + wc_) * 32 + nt_ * 16 + r_;
      s1 += rS[idx]; s2 += rQ[idx];
    }
    atomicAdd(&wsum[64 + c], s1);
    atomicAdd(&wsum[128 + c], s2);
  }
}

// ---------------- K4: abn apply + relu + center-mask zero (bf16 in, 8-wide) -
__global__ __launch_bounds__(256) void k_final(
    const unsigned short* __restrict__ out_pre, const float* __restrict__ mask,
    const float* __restrict__ abn_g, const float* __restrict__ abn_b,
    const float* __restrict__ ws, float* __restrict__ out) {
  __shared__ float sc[64], sh[64];
  if (threadIdx.x < 64) {
    int c = threadIdx.x;
    float n0 = fmaxf(ws[15], 1.f);
    float mean = ws[64 + c] / n0;
    float var = ws[128 + c] / n0 - mean * mean;
    float s_ = abn_g[c] * rsqrtf(var + EPS);
    sc[c] = s_; sh[c] = abn_b[c] - mean * s_;
  }
  __syncthreads();
  int i8 = (blockIdx.x * 256 + threadIdx.x) * 8;
  if (i8 >= B_ * 64 * HW_) return;
  int c = (i8 >> 16) & 63;
  int b = i8 >> 22;
  int s = i8 & (HW_ - 1);
  uint4 v = *reinterpret_cast<const uint4*>(out_pre + i8);
  float4 m0 = *reinterpret_cast<const float4*>(mask + (size_t)b * HW_ + s);
  float4 m1 = *reinterpret_cast<const float4*>(mask + (size_t)b * HW_ + s + 4);
  float scv = sc[c], shv = sh[c];
  float4 o0, o1;
  o0.x = (m0.x > 0.f) ? fmaxf(bf2f(v.x & 0xffffu) * scv + shv, 0.f) : 0.f;
  o0.y = (m0.y > 0.f) ? fmaxf(bf2f(v.x >> 16) * scv + shv, 0.f) : 0.f;
  o0.z = (m0.z > 0.f) ? fmaxf(bf2f(v.y & 0xffffu) * scv + shv, 0.f) : 0.f;
  o0.w = (m0.w > 0.f) ? fmaxf(bf2f(v.y >> 16) * scv + shv, 0.f) : 0.f;
  o1.x = (m1.x > 0.f) ? fmaxf(bf2f(v.z & 0xffffu) * scv + shv, 0.f) : 0.f;
  o1.y = (m1.y > 0.f) ? fmaxf(bf2f(v.z >> 16) * scv + shv, 0.f) : 0.f;
  o1.z = (m1.z > 0.f) ? fmaxf(bf2f(v.w & 0xffffu) * scv + shv, 0.f) : 0.f;
  o1.w = (m1.w > 0.f) ? fmaxf(bf2f(v.w >> 16) * scv + shv, 0.f) : 0.f;
  *reinterpret_cast<float4*>(out + i8) = o0;
  *reinterpret_cast<float4*>(out + i8 + 4) = o1;
}

extern "C" void kernel_launch(void* const* d_in, const int* in_sizes, int n_in,
                              void* d_out, int out_size, void* d_ws, size_t ws_size,
                              hipStream_t stream) {
  const float* x      = (const float*)d_in[0];
  const float* mask   = (const float*)d_in[1];
  const float* w1     = (const float*)d_in[2];
  const float* bn1_g  = (const float*)d_in[3];
  const float* bn1_b  = (const float*)d_in[4];
  const float* w2     = (const float*)d_in[5];
  const float* b2     = (const float*)d_in[6];
  const float* g1     = (const float*)d_in[7];
  const float* gbn1_g = (const float*)d_in[8];
  const float* gbn1_b = (const float*)d_in[9];
  const float* g2     = (const float*)d_in[10];
  const float* gbn2_g = (const float*)d_in[11];
  const float* gbn2_b = (const float*)d_in[12];
  const float* w_agg  = (const float*)d_in[13];
  const float* abn_g  = (const float*)d_in[14];
  const float* abn_b  = (const float*)d_in[15];
  float* out = (float*)d_out;

  size_t need = 1024 + (size_t)NPIX * 64 * 2;  // bf16 out_pre
  if (ws_size < need) return;

  float* wsf = (float*)d_ws;
  unsigned short* out_pre = (unsigned short*)((char*)d_ws + 1024);

  hipMemsetAsync(d_ws, 0, 1024, stream);
  k_stats1<<<512, 256, 0, stream>>>(x, mask, wsf);
  k_stats2<<<1024, 256, 0, stream>>>(x, mask, g1, gbn1_g, gbn1_b, g2, wsf);
  k_fused<<<512, 512, 0, stream>>>(x, mask, w1, bn1_g, bn1_b, w2, b2, g1,
                                   gbn1_g, gbn1_b, g2, gbn2_g, gbn2_b, w_agg,
                                   wsf, out_pre, wsf);
  k_final<<<4096, 256, 0, stream>>>(out_pre, mask, abn_g, abn_b, wsf, out);
}